// Round 20
// baseline (305.623 us; speedup 1.0000x reference)
//
#include <hip/hip_runtime.h>

#define DIMC 2048
#define NSEQ 2048
#define NBATCH 2
#define NH 32
#define DH 64
#define BHEADS (NBATCH*NH)      // 64
#define MROWS (NBATCH*NSEQ)     // 4096
#define NQKV (3*DIMC)           // 6144

typedef __attribute__((ext_vector_type(8))) short short8;
typedef __attribute__((ext_vector_type(4))) float f32x4;
typedef __attribute__((ext_vector_type(4))) unsigned int uint4v;
typedef __attribute__((ext_vector_type(2))) unsigned int u32x2;

static __device__ __forceinline__ unsigned short f2bf(float f) {
  union { float f; unsigned int u; } v; v.f = f;
  unsigned int r = (v.u + 0x7FFFu + ((v.u >> 16) & 1u)) >> 16;
  return (unsigned short)r;
}

static __device__ __forceinline__ unsigned int cvt_pk_bf16(float lo, float hi) {
  unsigned int r;
  asm("v_cvt_pk_bf16_f32 %0, %1, %2" : "=v"(r) : "v"(lo), "v"(hi));
  return r;
}

static __device__ __forceinline__ float fexp2(float x) {
  float r;
  asm("v_exp_f32 %0, %1" : "=v"(r) : "v"(x));
  return r;
}

#define BAR()    __builtin_amdgcn_s_barrier()
#define FENCE()  asm volatile("" ::: "memory")
#define LGKM0()  asm volatile("s_waitcnt lgkmcnt(0)" ::: "memory")
#define VM(n)    asm volatile("s_waitcnt vmcnt(" #n ")" ::: "memory")

// ------- fused fp32->bf16 convert (x, Wqkv, Wout) + cos/sin table -----------
__global__ __launch_bounds__(256) void cvt_all(
    const float* __restrict__ x, const float* __restrict__ wqkv,
    const float* __restrict__ wout, const float* __restrict__ freqs,
    unsigned short* __restrict__ xb, unsigned short* __restrict__ wqkvb,
    unsigned short* __restrict__ woutb, float2* __restrict__ cst) {
  const int n1 = MROWS * DIMC / 8;
  const int n2 = n1 + NQKV * DIMC / 8;
  const int n3 = n2 + DIMC * DIMC / 8;
  const int n4 = n3 + NSEQ * DH / 8;
  int i = blockIdx.x * blockDim.x + threadIdx.x;
  int stride = gridDim.x * blockDim.x;
  for (; i < n4; i += stride) {
    if (i < n3) {
      const float* src; unsigned short* dst; int j;
      if (i < n1)      { src = x;    dst = xb;    j = i; }
      else if (i < n2) { src = wqkv; dst = wqkvb; j = i - n1; }
      else             { src = wout; dst = woutb; j = i - n2; }
      const float4* p = (const float4*)src + (size_t)j * 2;
      float4 a = p[0], b = p[1];
      union { unsigned short u[8]; uint4v v; } o;
      o.u[0] = f2bf(a.x); o.u[1] = f2bf(a.y); o.u[2] = f2bf(a.z); o.u[3] = f2bf(a.w);
      o.u[4] = f2bf(b.x); o.u[5] = f2bf(b.y); o.u[6] = f2bf(b.z); o.u[7] = f2bf(b.w);
      *((uint4v*)dst + j) = o.v;
    } else {
      int j = i - n3;                       // 8 freqs -> 8 float2
      const float4* p = (const float4*)freqs + (size_t)j * 2;
      float4 a = p[0], b = p[1];
      float2* d = cst + (size_t)j * 8;
      d[0] = make_float2(cosf(a.x), sinf(a.x));
      d[1] = make_float2(cosf(a.y), sinf(a.y));
      d[2] = make_float2(cosf(a.z), sinf(a.z));
      d[3] = make_float2(cosf(a.w), sinf(a.w));
      d[4] = make_float2(cosf(b.x), sinf(b.x));
      d[5] = make_float2(cosf(b.y), sinf(b.y));
      d[6] = make_float2(cosf(b.z), sinf(b.z));
      d[7] = make_float2(cosf(b.w), sinf(b.w));
    }
  }
}

// ---------------- GEMM: C[128,256-tile] = A[M,K] * B[N,K]^T -----------------
// R19 config + R20: removed explicit LGKM0 full-drain — ds_reads are
// compiler-visible, so hipcc emits precise counted lgkmcnt before each
// dependent MFMA (first MFMAs overlap tail ds_reads). Reads cannot hoist
// above BAR+FENCE nor sink below VM(n) (asm memory clobbers), so the R19
// single-barrier invariants hold:
//  RAW: LDAB(tile i) reads a slot drained by VM(3) before phase i-1's BAR.
//  WAR: STAGE(tile i+2) overwrites tile i-1's slot, whose reads retired
//       before that same BAR.
// GM=8 grouped walk after XCD remap (R18: FETCH 330->90 MB).
#define QSCALE 0.18033688011112042f   // (1/8) * log2(e)
#define SLOT 24576                     // A 8KB + B 16KB per K-tile

template<int EPI>
__global__ __launch_bounds__(512, 1) void gemm128(
    const unsigned short* __restrict__ A,
    const unsigned short* __restrict__ Bm,
    int Kdim, int Ncols,
    float* __restrict__ Cout,
    unsigned short* __restrict__ qo, unsigned short* __restrict__ ko,
    unsigned short* __restrict__ vo, const float2* __restrict__ cs)
{
  extern __shared__ char Lds[];   // 73728 bytes (3 slots)
  const int t = threadIdx.x;
  const int w = t >> 6, lane = t & 63, lr = lane & 15, g = lane >> 4;
  const int wm = w >> 2, wn = w & 3;
  const int gxs = (g * 16) ^ (((lr >> 1) & 3) << 4);   // swizzled read offset

  // XCD-aware bijective swizzle, then GM=8 grouped walk for L2 locality.
  const int nx = gridDim.x;
  int orig = blockIdx.y * nx + blockIdx.x;
  int cpx = (nx * gridDim.y) >> 3;
  int id = (orig & 7) * cpx + (orig >> 3);
  const int gsz = 8 * nx;
  int gid = id / gsz;
  int rem = id - gid * gsz;
  const int m0 = (gid * 8 + (rem & 7)) * 128;
  const int n0 = (rem >> 3) * 256;

  const int rowt = t >> 2;
  const int colt = ((t & 3) ^ ((t >> 3) & 3)) * 8;
  const unsigned short* Abase = A + (size_t)(m0 + rowt) * Kdim + colt;
  const unsigned short* Bbase = Bm + (size_t)(n0 + rowt) * Kdim + colt;
  char* dstw = Lds + w * 1024;

  auto STAGE = [&](int sbuf, int T) {
    const unsigned short* sa = Abase + T * 32;
    const unsigned short* sb = Bbase + T * 32;
    __builtin_amdgcn_global_load_lds(
        (const __attribute__((address_space(1))) void*)sa,
        (__attribute__((address_space(3))) void*)(dstw + sbuf), 16, 0, 0);
    __builtin_amdgcn_global_load_lds(
        (const __attribute__((address_space(1))) void*)sb,
        (__attribute__((address_space(3))) void*)(dstw + sbuf + 8192), 16, 0, 0);
    __builtin_amdgcn_global_load_lds(
        (const __attribute__((address_space(1))) void*)(sb + (size_t)128 * Kdim),
        (__attribute__((address_space(3))) void*)(dstw + sbuf + 16384), 16, 0, 0);
  };

  short8 Af[4], Bf[4];
  auto LDAB = [&](int rb) {
    const char* ap = Lds + rb + (wm * 64 + lr) * 64 + gxs;
    const char* bp = Lds + rb + 8192 + (wn * 64 + lr) * 64 + gxs;
    #pragma unroll
    for (int m = 0; m < 4; m++) Af[m] = *(const short8*)(ap + m * 1024);
    #pragma unroll
    for (int n = 0; n < 4; n++) Bf[n] = *(const short8*)(bp + n * 1024);
  };

  f32x4 acc[4][4];
  f32x4 zero = {0.0f, 0.0f, 0.0f, 0.0f};
  #pragma unroll
  for (int i = 0; i < 4; i++)
    #pragma unroll
    for (int j = 0; j < 4; j++) acc[i][j] = zero;

  // ---- prologue: stage tiles 0,1; drain tile 0 collectively ----
  STAGE(0, 0); STAGE(SLOT, 1);
  VM(3);
  BAR(); FENCE();

  const int NT = Kdim >> 5;    // 64 K-tiles
  int rb = 0, sb = 2 * SLOT;
  for (int i = 0; i < NT; i++) {
    LDAB(rb);
    if (i + 2 < NT) STAGE(sb, i + 2);
    __builtin_amdgcn_s_setprio(1);
    #pragma unroll
    for (int m = 0; m < 4; m++)
      #pragma unroll
      for (int n = 0; n < 4; n++)
        acc[m][n] = __builtin_amdgcn_mfma_f32_16x16x32_bf16(Af[m], Bf[n], acc[m][n], 0, 0, 0);
    __builtin_amdgcn_s_setprio(0);
    if (i < NT - 2) { VM(3); } else { VM(0); }
    BAR(); FENCE();
    rb += SLOT; if (rb == 3 * SLOT) rb = 0;
    sb += SLOT; if (sb == 3 * SLOT) sb = 0;
  }

  // ---- epilogue ----
  if (EPI == 0) {
    #pragma unroll
    for (int m = 0; m < 4; m++) {
      #pragma unroll
      for (int r = 0; r < 4; r++) {
        int row = m0 + wm * 64 + m * 16 + g * 4 + r;
        #pragma unroll
        for (int n = 0; n < 4; n++)
          Cout[(size_t)row * Ncols + (n0 + wn * 64 + n * 16 + lr)] = acc[m][n][r];
      }
    }
  } else {
    const int which = n0 >> 11;
    const int head = ((n0 & 2047) + wn * 64) >> 6;
    #pragma unroll
    for (int m = 0; m < 4; m++) {
      #pragma unroll
      for (int r = 0; r < 4; r++) {
        int row = m0 + wm * 64 + m * 16 + g * 4 + r;
        int b = row >> 11, ntok = row & 2047;
        size_t obase = ((size_t)(b * NH + head) * NSEQ + ntok) * DH;
        #pragma unroll
        for (int n = 0; n < 4; n++) {
          int d = n * 16 + lr;
          float val = acc[m][n][r];
          if (which == 2) {
            vo[obase + d] = f2bf(val);
          } else {
            float other = acc[m][n ^ 2][r];
            float2 c2 = cs[ntok * DH + d];
            float rot = (d < 32) ? (val * c2.x - other * c2.y)
                                 : (val * c2.x + other * c2.y);
            if (which == 0) qo[obase + d] = f2bf(rot * QSCALE);
            else            ko[obase + d] = f2bf(rot);
          }
        }
      }
    }
  }
}

// ---------------- flash attention: 4 waves x 32 q, KVBLK=64, K/V dbuf -------
// (unchanged from R14)
__global__ __launch_bounds__(256, 3) void attn_fa(
    const unsigned short* __restrict__ qb,
    const unsigned short* __restrict__ kb,
    const unsigned short* __restrict__ vb,
    unsigned short* __restrict__ aob)
{
  __shared__ __align__(16) unsigned short Kl[2][64 * 64];   // XOR-swizzled content
  __shared__ __align__(16) unsigned short Vt[2][64 * 72];   // [d][k + pad8]
  __shared__ __align__(16) unsigned short Pl[4][32 * 72];   // per-wave [q][k + pad8]

  const int t = threadIdx.x;
  const int w = t >> 6, lane = t & 63, lr = lane & 15, g = lane >> 4;
  const int bh = blockIdx.y;
  const int q0 = blockIdx.x * 128 + w * 32;
  const size_t hbase = (size_t)bh * NSEQ * DH;

  short8 qf[2][2];
  #pragma unroll
  for (int qt = 0; qt < 2; qt++)
    #pragma unroll
    for (int hf = 0; hf < 2; hf++)
      qf[qt][hf] = *(const short8*)(qb + hbase + (size_t)(q0 + qt * 16 + lr) * DH + hf * 32 + g * 8);

  f32x4 zero = {0.0f, 0.0f, 0.0f, 0.0f};
  f32x4 oacc[2][4];
  #pragma unroll
  for (int qt = 0; qt < 2; qt++)
    #pragma unroll
    for (int dv = 0; dv < 4; dv++) oacc[qt][dv] = zero;
  float mrun[2] = {-1e30f, -1e30f};
  float lrun[2] = {0.0f, 0.0f};

  int kro[2], kdo_[2];
  #pragma unroll
  for (int c = 0; c < 2; c++) {
    int b = w * 2048 + c * 1024 + lane * 16;
    int row = b >> 7;
    int off = b ^ ((row & 7) << 4);
    kro[c] = row;
    kdo_[c] = (off >> 1) & 63;
  }
  const int vr0 = (t & 31) * 2;
  const int vhv = (t >> 5) * 8;

  unsigned short* prow0 = &Pl[w][lr * 72];
  unsigned short* prow1 = &Pl[w][(16 + lr) * 72];

  auto STAGE_K = [&](int buf, int kv0) {
    #pragma unroll
    for (int c = 0; c < 2; c++) {
      const unsigned short* src = kb + hbase + (size_t)(kv0 + kro[c]) * DH + kdo_[c];
      __builtin_amdgcn_global_load_lds(
          (const __attribute__((address_space(1))) void*)src,
          (__attribute__((address_space(3))) void*)(&Kl[buf][0] + w * 1024 + c * 512), 16, 0, 0);
    }
  };
  auto LOAD_V = [&](int kv0, short8& v0, short8& v1) {
    const unsigned short* s0 = vb + hbase + (size_t)(kv0 + vr0) * DH + vhv;
    v0 = *(const short8*)(s0);
    v1 = *(const short8*)(s0 + DH);
  };
  auto WRITE_V = [&](int buf, short8 v0, short8 v1) {
    #pragma unroll
    for (int j = 0; j < 8; j++) {
      unsigned int p = ((unsigned short)v0[j]) | (((unsigned int)(unsigned short)v1[j]) << 16);
      *(unsigned int*)&Vt[buf][(vhv + j) * 72 + vr0] = p;
    }
  };

  // ---- prologue: stage chunk 0 -> buf 0 ----
  {
    short8 pv0, pv1;
    STAGE_K(0, 0);
    LOAD_V(0, pv0, pv1);
    VM(0);
    WRITE_V(0, pv0, pv1);
    LGKM0();
    BAR(); FENCE();
  }

  const int NC = NSEQ / 64;   // 32 chunks
  for (int it = 0; it < NC; it++) {
    const int cur = it & 1;
    const bool more = (it + 1 < NC);
    short8 nv0, nv1;
    if (more) {
      STAGE_K(cur ^ 1, (it + 1) * 64);
      LOAD_V((it + 1) * 64, nv0, nv1);
    }

    const char* Kb = (const char*)&Kl[cur][0];
    const unsigned short* Vb = &Vt[cur][0];

    // ---- QK^T swapped: S^T[k][q] ----
    f32x4 s[2][4];
    #pragma unroll
    for (int kt = 0; kt < 4; kt++) {
      int row = kt * 16 + lr;
      int sw = (row & 7) << 4;
      int byteA = (row * 128 + g * 16) ^ sw;
      int byteB = (row * 128 + 64 + g * 16) ^ sw;
      short8 kA = *(const short8*)(Kb + byteA);
      short8 kB = *(const short8*)(Kb + byteB);
      __builtin_amdgcn_s_setprio(1);
      #pragma unroll
      for (int qt = 0; qt < 2; qt++) {
        f32x4 a0 = __builtin_amdgcn_mfma_f32_16x16x32_bf16(kA, qf[qt][0], zero, 0, 0, 0);
        s[qt][kt] = __builtin_amdgcn_mfma_f32_16x16x32_bf16(kB, qf[qt][1], a0, 0, 0, 0);
      }
      __builtin_amdgcn_s_setprio(0);
    }

    // ---- tile max ----
    float nm[2];
    #pragma unroll
    for (int qt = 0; qt < 2; qt++) {
      f32x4 m01 = s[qt][0];
      #pragma unroll
      for (int kt = 1; kt < 4; kt++) {
        f32x4 sv = s[qt][kt];
        m01[0] = fmaxf(m01[0], sv[0]); m01[1] = fmaxf(m01[1], sv[1]);
        m01[2] = fmaxf(m01[2], sv[2]); m01[3] = fmaxf(m01[3], sv[3]);
      }
      float v = fmaxf(fmaxf(m01[0], m01[1]), fmaxf(m01[2], m01[3]));
      v = fmaxf(v, __shfl_xor(v, 16));
      v = fmaxf(v, __shfl_xor(v, 32));
      nm[qt] = v;
    }

    // ---- defer-rescale (THR=8, base-2 domain) ----
    if (!__all(fmaxf(nm[0] - mrun[0], nm[1] - mrun[1]) <= 8.0f)) {
      const int sb = (lane & 48) + ((lane & 48) >> 2);
      #pragma unroll
      for (int qt = 0; qt < 2; qt++) {
        float m2 = fmaxf(mrun[qt], nm[qt]);
        float cc = fexp2(mrun[qt] - m2);
        mrun[qt] = m2;
        lrun[qt] *= cc;
        float c0r = __shfl(cc, sb + 0);
        float c1r = __shfl(cc, sb + 1);
        float c2r = __shfl(cc, sb + 2);
        float c3r = __shfl(cc, sb + 3);
        #pragma unroll
        for (int dv = 0; dv < 4; dv++) {
          f32x4 a = oacc[qt][dv];
          a[0] *= c0r; a[1] *= c1r; a[2] *= c2r; a[3] *= c3r;
          oacc[qt][dv] = a;
        }
      }
    }

    // ---- P = exp2(S - m), packed bf16 -> per-wave LDS ----
    #pragma unroll
    for (int qt = 0; qt < 2; qt++) {
      float mq = mrun[qt];
      float ls = 0.0f;
      unsigned short* prow = qt ? prow1 : prow0;
      #pragma unroll
      for (int kt = 0; kt < 4; kt++) {
        f32x4 sv = s[qt][kt];
        float p0 = fexp2(sv[0] - mq), p1 = fexp2(sv[1] - mq);
        float p2 = fexp2(sv[2] - mq), p3 = fexp2(sv[3] - mq);
        ls += (p0 + p1) + (p2 + p3);
        u32x2 uu;
        uu.x = cvt_pk_bf16(p0, p1);
        uu.y = cvt_pk_bf16(p2, p3);
        *(u32x2*)(prow + kt * 16 + g * 4) = uu;
      }
      ls += __shfl_xor(ls, 16);
      ls += __shfl_xor(ls, 32);
      lrun[qt] += ls;
    }

    // ---- PV ----
    #pragma unroll
    for (int c0 = 0; c0 < 2; c0++) {
      short8 pa0 = *(const short8*)(prow0 + c0 * 32 + g * 8);
      short8 pa1 = *(const short8*)(prow1 + c0 * 32 + g * 8);
      __builtin_amdgcn_s_setprio(1);
      #pragma unroll
      for (int dv = 0; dv < 4; dv++) {
        short8 vf = *(const short8*)&Vb[(dv * 16 + lr) * 72 + c0 * 32 + g * 8];
        oacc[0][dv] = __builtin_amdgcn_mfma_f32_16x16x32_bf16(pa0, vf, oacc[0][dv], 0, 0, 0);
        oacc[1][dv] = __builtin_amdgcn_mfma_f32_16x16x32_bf16(pa1, vf, oacc[1][dv], 0, 0, 0);
      }
      __builtin_amdgcn_s_setprio(0);
    }

    // ---- finish staging chunk i+1 ----
    if (more) {
      VM(0);                       // K DMA + V regs landed (collective via BAR)
      WRITE_V(cur ^ 1, nv0, nv1);
    }
    LGKM0();
    BAR(); FENCE();
  }

  // ---- epilogue: normalize and store [b][n][h*64+d] ----
  const int b = bh >> 5, h = bh & 31;
  const int sb = (lane & 48) + ((lane & 48) >> 2);
  #pragma unroll
  for (int qt = 0; qt < 2; qt++) {
    float inv = 1.0f / lrun[qt];
    float ir[4];
    ir[0] = __shfl(inv, sb + 0);
    ir[1] = __shfl(inv, sb + 1);
    ir[2] = __shfl(inv, sb + 2);
    ir[3] = __shfl(inv, sb + 3);
    #pragma unroll
    for (int r = 0; r < 4; r++) {
      int ntok = q0 + qt * 16 + g * 4 + r;
      size_t ob = ((size_t)(b * NSEQ + ntok)) * DIMC + h * DH;
      #pragma unroll
      for (int dv = 0; dv < 4; dv++)
        aob[ob + dv * 16 + lr] = f2bf(oacc[qt][dv][r] * ir[r]);
    }
  }
}

// ---------------------------------------------------------------------------
extern "C" void kernel_launch(void* const* d_in, const int* in_sizes, int n_in,
                              void* d_out, int out_size, void* d_ws, size_t ws_size,
                              hipStream_t stream) {
  const float* x     = (const float*)d_in[0];
  const float* freqs = (const float*)d_in[1];
  const float* Wqkv  = (const float*)d_in[2];
  const float* Wout  = (const float*)d_in[3];
  float* out = (float*)d_out;

  char* ws = (char*)d_ws;
  size_t off = 0;
  auto alloc = [&](size_t bytes) {
    void* p = ws + off;
    off += (bytes + 255) & ~(size_t)255;
    return p;
  };
  unsigned short* xb    = (unsigned short*)alloc((size_t)MROWS * DIMC * 2);
  unsigned short* wqkvb = (unsigned short*)alloc((size_t)NQKV * DIMC * 2);
  unsigned short* woutb = (unsigned short*)alloc((size_t)DIMC * DIMC * 2);
  unsigned short* qbuf  = (unsigned short*)alloc((size_t)BHEADS * NSEQ * DH * 2);
  unsigned short* kbuf  = (unsigned short*)alloc((size_t)BHEADS * NSEQ * DH * 2);
  unsigned short* vbuf  = (unsigned short*)alloc((size_t)BHEADS * NSEQ * DH * 2);
  float2* cst           = (float2*)alloc((size_t)NSEQ * DH * sizeof(float2));
  unsigned short* aob   = xb;   // xb dead after gemm1; reuse for attn output

  (void)hipFuncSetAttribute((const void*)gemm128<1>,
      hipFuncAttributeMaxDynamicSharedMemorySize, 3 * SLOT);
  (void)hipFuncSetAttribute((const void*)gemm128<0>,
      hipFuncAttributeMaxDynamicSharedMemorySize, 3 * SLOT);

  cvt_all<<<2048, 256, 0, stream>>>(x, Wqkv, Wout, freqs, xb, wqkvb, woutb, cst);

  gemm128<1><<<dim3(NQKV / 256, MROWS / 128), 512, 3 * SLOT, stream>>>(
      xb, wqkvb, DIMC, NQKV, nullptr, qbuf, kbuf, vbuf, cst);

  attn_fa<<<dim3(NSEQ / 128, BHEADS), 256, 0, stream>>>(qbuf, kbuf, vbuf, aob);

  gemm128<0><<<dim3(DIMC / 256, MROWS / 128), 512, 3 * SLOT, stream>>>(
      aob, woutb, DIMC, DIMC, out, nullptr, nullptr, nullptr, nullptr);
}

// Round 21
// 304.954 us; speedup vs baseline: 1.0022x; 1.0022x over previous
//
#include <hip/hip_runtime.h>

#define DIMC 2048
#define NSEQ 2048
#define NBATCH 2
#define NH 32
#define DH 64
#define BHEADS (NBATCH*NH)      // 64
#define MROWS (NBATCH*NSEQ)     // 4096
#define NQKV (3*DIMC)           // 6144

typedef __attribute__((ext_vector_type(8))) short short8;
typedef __attribute__((ext_vector_type(4))) float f32x4;
typedef __attribute__((ext_vector_type(4))) unsigned int uint4v;
typedef __attribute__((ext_vector_type(2))) unsigned int u32x2;

static __device__ __forceinline__ unsigned short f2bf(float f) {
  union { float f; unsigned int u; } v; v.f = f;
  unsigned int r = (v.u + 0x7FFFu + ((v.u >> 16) & 1u)) >> 16;
  return (unsigned short)r;
}

static __device__ __forceinline__ unsigned int cvt_pk_bf16(float lo, float hi) {
  unsigned int r;
  asm("v_cvt_pk_bf16_f32 %0, %1, %2" : "=v"(r) : "v"(lo), "v"(hi));
  return r;
}

static __device__ __forceinline__ float fexp2(float x) {
  float r;
  asm("v_exp_f32 %0, %1" : "=v"(r) : "v"(x));
  return r;
}

#define BAR()    __builtin_amdgcn_s_barrier()
#define FENCE()  asm volatile("" ::: "memory")
#define LGKM0()  asm volatile("s_waitcnt lgkmcnt(0)" ::: "memory")
#define VM(n)    asm volatile("s_waitcnt vmcnt(" #n ")" ::: "memory")

// ------- fused fp32->bf16 convert (x, Wqkv, Wout) + cos/sin table -----------
__global__ __launch_bounds__(256) void cvt_all(
    const float* __restrict__ x, const float* __restrict__ wqkv,
    const float* __restrict__ wout, const float* __restrict__ freqs,
    unsigned short* __restrict__ xb, unsigned short* __restrict__ wqkvb,
    unsigned short* __restrict__ woutb, float2* __restrict__ cst) {
  const int n1 = MROWS * DIMC / 8;
  const int n2 = n1 + NQKV * DIMC / 8;
  const int n3 = n2 + DIMC * DIMC / 8;
  const int n4 = n3 + NSEQ * DH / 8;
  int i = blockIdx.x * blockDim.x + threadIdx.x;
  int stride = gridDim.x * blockDim.x;
  for (; i < n4; i += stride) {
    if (i < n3) {
      const float* src; unsigned short* dst; int j;
      if (i < n1)      { src = x;    dst = xb;    j = i; }
      else if (i < n2) { src = wqkv; dst = wqkvb; j = i - n1; }
      else             { src = wout; dst = woutb; j = i - n2; }
      const float4* p = (const float4*)src + (size_t)j * 2;
      float4 a = p[0], b = p[1];
      union { unsigned short u[8]; uint4v v; } o;
      o.u[0] = f2bf(a.x); o.u[1] = f2bf(a.y); o.u[2] = f2bf(a.z); o.u[3] = f2bf(a.w);
      o.u[4] = f2bf(b.x); o.u[5] = f2bf(b.y); o.u[6] = f2bf(b.z); o.u[7] = f2bf(b.w);
      *((uint4v*)dst + j) = o.v;
    } else {
      int j = i - n3;                       // 8 freqs -> 8 float2
      const float4* p = (const float4*)freqs + (size_t)j * 2;
      float4 a = p[0], b = p[1];
      float2* d = cst + (size_t)j * 8;
      d[0] = make_float2(cosf(a.x), sinf(a.x));
      d[1] = make_float2(cosf(a.y), sinf(a.y));
      d[2] = make_float2(cosf(a.z), sinf(a.z));
      d[3] = make_float2(cosf(a.w), sinf(a.w));
      d[4] = make_float2(cosf(b.x), sinf(b.x));
      d[5] = make_float2(cosf(b.y), sinf(b.y));
      d[6] = make_float2(cosf(b.z), sinf(b.z));
      d[7] = make_float2(cosf(b.w), sinf(b.w));
    }
  }
}

// ---------------- GEMM: C[128,256-tile] = A[M,K] * B[N,K]^T -----------------
// R19 config + R20: removed explicit LGKM0 full-drain — ds_reads are
// compiler-visible, so hipcc emits precise counted lgkmcnt before each
// dependent MFMA (first MFMAs overlap tail ds_reads). Reads cannot hoist
// above BAR+FENCE nor sink below VM(n) (asm memory clobbers), so the R19
// single-barrier invariants hold:
//  RAW: LDAB(tile i) reads a slot drained by VM(3) before phase i-1's BAR.
//  WAR: STAGE(tile i+2) overwrites tile i-1's slot, whose reads retired
//       before that same BAR.
// GM=8 grouped walk after XCD remap (R18: FETCH 330->90 MB).
#define QSCALE 0.18033688011112042f   // (1/8) * log2(e)
#define SLOT 24576                     // A 8KB + B 16KB per K-tile

template<int EPI>
__global__ __launch_bounds__(512, 1) void gemm128(
    const unsigned short* __restrict__ A,
    const unsigned short* __restrict__ Bm,
    int Kdim, int Ncols,
    float* __restrict__ Cout,
    unsigned short* __restrict__ qo, unsigned short* __restrict__ ko,
    unsigned short* __restrict__ vo, const float2* __restrict__ cs)
{
  extern __shared__ char Lds[];   // 73728 bytes (3 slots)
  const int t = threadIdx.x;
  const int w = t >> 6, lane = t & 63, lr = lane & 15, g = lane >> 4;
  const int wm = w >> 2, wn = w & 3;
  const int gxs = (g * 16) ^ (((lr >> 1) & 3) << 4);   // swizzled read offset

  // XCD-aware bijective swizzle, then GM=8 grouped walk for L2 locality.
  const int nx = gridDim.x;
  int orig = blockIdx.y * nx + blockIdx.x;
  int cpx = (nx * gridDim.y) >> 3;
  int id = (orig & 7) * cpx + (orig >> 3);
  const int gsz = 8 * nx;
  int gid = id / gsz;
  int rem = id - gid * gsz;
  const int m0 = (gid * 8 + (rem & 7)) * 128;
  const int n0 = (rem >> 3) * 256;

  const int rowt = t >> 2;
  const int colt = ((t & 3) ^ ((t >> 3) & 3)) * 8;
  const unsigned short* Abase = A + (size_t)(m0 + rowt) * Kdim + colt;
  const unsigned short* Bbase = Bm + (size_t)(n0 + rowt) * Kdim + colt;
  char* dstw = Lds + w * 1024;

  auto STAGE = [&](int sbuf, int T) {
    const unsigned short* sa = Abase + T * 32;
    const unsigned short* sb = Bbase + T * 32;
    __builtin_amdgcn_global_load_lds(
        (const __attribute__((address_space(1))) void*)sa,
        (__attribute__((address_space(3))) void*)(dstw + sbuf), 16, 0, 0);
    __builtin_amdgcn_global_load_lds(
        (const __attribute__((address_space(1))) void*)sb,
        (__attribute__((address_space(3))) void*)(dstw + sbuf + 8192), 16, 0, 0);
    __builtin_amdgcn_global_load_lds(
        (const __attribute__((address_space(1))) void*)(sb + (size_t)128 * Kdim),
        (__attribute__((address_space(3))) void*)(dstw + sbuf + 16384), 16, 0, 0);
  };

  short8 Af[4], Bf[4];
  auto LDAB = [&](int rb) {
    const char* ap = Lds + rb + (wm * 64 + lr) * 64 + gxs;
    const char* bp = Lds + rb + 8192 + (wn * 64 + lr) * 64 + gxs;
    #pragma unroll
    for (int m = 0; m < 4; m++) Af[m] = *(const short8*)(ap + m * 1024);
    #pragma unroll
    for (int n = 0; n < 4; n++) Bf[n] = *(const short8*)(bp + n * 1024);
  };

  f32x4 acc[4][4];
  f32x4 zero = {0.0f, 0.0f, 0.0f, 0.0f};
  #pragma unroll
  for (int i = 0; i < 4; i++)
    #pragma unroll
    for (int j = 0; j < 4; j++) acc[i][j] = zero;

  // ---- prologue: stage tiles 0,1; drain tile 0 collectively ----
  STAGE(0, 0); STAGE(SLOT, 1);
  VM(3);
  BAR(); FENCE();

  const int NT = Kdim >> 5;    // 64 K-tiles
  int rb = 0, sb = 2 * SLOT;
  for (int i = 0; i < NT; i++) {
    LDAB(rb);
    if (i + 2 < NT) STAGE(sb, i + 2);
    __builtin_amdgcn_s_setprio(1);
    #pragma unroll
    for (int m = 0; m < 4; m++)
      #pragma unroll
      for (int n = 0; n < 4; n++)
        acc[m][n] = __builtin_amdgcn_mfma_f32_16x16x32_bf16(Af[m], Bf[n], acc[m][n], 0, 0, 0);
    __builtin_amdgcn_s_setprio(0);
    if (i < NT - 2) { VM(3); } else { VM(0); }
    BAR(); FENCE();
    rb += SLOT; if (rb == 3 * SLOT) rb = 0;
    sb += SLOT; if (sb == 3 * SLOT) sb = 0;
  }

  // ---- epilogue ----
  if (EPI == 0) {
    #pragma unroll
    for (int m = 0; m < 4; m++) {
      #pragma unroll
      for (int r = 0; r < 4; r++) {
        int row = m0 + wm * 64 + m * 16 + g * 4 + r;
        #pragma unroll
        for (int n = 0; n < 4; n++)
          Cout[(size_t)row * Ncols + (n0 + wn * 64 + n * 16 + lr)] = acc[m][n][r];
      }
    }
  } else {
    const int which = n0 >> 11;
    const int head = ((n0 & 2047) + wn * 64) >> 6;
    #pragma unroll
    for (int m = 0; m < 4; m++) {
      #pragma unroll
      for (int r = 0; r < 4; r++) {
        int row = m0 + wm * 64 + m * 16 + g * 4 + r;
        int b = row >> 11, ntok = row & 2047;
        size_t obase = ((size_t)(b * NH + head) * NSEQ + ntok) * DH;
        #pragma unroll
        for (int n = 0; n < 4; n++) {
          int d = n * 16 + lr;
          float val = acc[m][n][r];
          if (which == 2) {
            vo[obase + d] = f2bf(val);
          } else {
            float other = acc[m][n ^ 2][r];
            float2 c2 = cs[ntok * DH + d];
            float rot = (d < 32) ? (val * c2.x - other * c2.y)
                                 : (val * c2.x + other * c2.y);
            if (which == 0) qo[obase + d] = f2bf(rot * QSCALE);
            else            ko[obase + d] = f2bf(rot);
          }
        }
      }
    }
  }
}

// ---------------- flash attention: 4 waves x 32 q, KVBLK=64, K/V dbuf -------
// (unchanged from R14)
__global__ __launch_bounds__(256, 3) void attn_fa(
    const unsigned short* __restrict__ qb,
    const unsigned short* __restrict__ kb,
    const unsigned short* __restrict__ vb,
    unsigned short* __restrict__ aob)
{
  __shared__ __align__(16) unsigned short Kl[2][64 * 64];   // XOR-swizzled content
  __shared__ __align__(16) unsigned short Vt[2][64 * 72];   // [d][k + pad8]
  __shared__ __align__(16) unsigned short Pl[4][32 * 72];   // per-wave [q][k + pad8]

  const int t = threadIdx.x;
  const int w = t >> 6, lane = t & 63, lr = lane & 15, g = lane >> 4;
  const int bh = blockIdx.y;
  const int q0 = blockIdx.x * 128 + w * 32;
  const size_t hbase = (size_t)bh * NSEQ * DH;

  short8 qf[2][2];
  #pragma unroll
  for (int qt = 0; qt < 2; qt++)
    #pragma unroll
    for (int hf = 0; hf < 2; hf++)
      qf[qt][hf] = *(const short8*)(qb + hbase + (size_t)(q0 + qt * 16 + lr) * DH + hf * 32 + g * 8);

  f32x4 zero = {0.0f, 0.0f, 0.0f, 0.0f};
  f32x4 oacc[2][4];
  #pragma unroll
  for (int qt = 0; qt < 2; qt++)
    #pragma unroll
    for (int dv = 0; dv < 4; dv++) oacc[qt][dv] = zero;
  float mrun[2] = {-1e30f, -1e30f};
  float lrun[2] = {0.0f, 0.0f};

  int kro[2], kdo_[2];
  #pragma unroll
  for (int c = 0; c < 2; c++) {
    int b = w * 2048 + c * 1024 + lane * 16;
    int row = b >> 7;
    int off = b ^ ((row & 7) << 4);
    kro[c] = row;
    kdo_[c] = (off >> 1) & 63;
  }
  const int vr0 = (t & 31) * 2;
  const int vhv = (t >> 5) * 8;

  unsigned short* prow0 = &Pl[w][lr * 72];
  unsigned short* prow1 = &Pl[w][(16 + lr) * 72];

  auto STAGE_K = [&](int buf, int kv0) {
    #pragma unroll
    for (int c = 0; c < 2; c++) {
      const unsigned short* src = kb + hbase + (size_t)(kv0 + kro[c]) * DH + kdo_[c];
      __builtin_amdgcn_global_load_lds(
          (const __attribute__((address_space(1))) void*)src,
          (__attribute__((address_space(3))) void*)(&Kl[buf][0] + w * 1024 + c * 512), 16, 0, 0);
    }
  };
  auto LOAD_V = [&](int kv0, short8& v0, short8& v1) {
    const unsigned short* s0 = vb + hbase + (size_t)(kv0 + vr0) * DH + vhv;
    v0 = *(const short8*)(s0);
    v1 = *(const short8*)(s0 + DH);
  };
  auto WRITE_V = [&](int buf, short8 v0, short8 v1) {
    #pragma unroll
    for (int j = 0; j < 8; j++) {
      unsigned int p = ((unsigned short)v0[j]) | (((unsigned int)(unsigned short)v1[j]) << 16);
      *(unsigned int*)&Vt[buf][(vhv + j) * 72 + vr0] = p;
    }
  };

  // ---- prologue: stage chunk 0 -> buf 0 ----
  {
    short8 pv0, pv1;
    STAGE_K(0, 0);
    LOAD_V(0, pv0, pv1);
    VM(0);
    WRITE_V(0, pv0, pv1);
    LGKM0();
    BAR(); FENCE();
  }

  const int NC = NSEQ / 64;   // 32 chunks
  for (int it = 0; it < NC; it++) {
    const int cur = it & 1;
    const bool more = (it + 1 < NC);
    short8 nv0, nv1;
    if (more) {
      STAGE_K(cur ^ 1, (it + 1) * 64);
      LOAD_V((it + 1) * 64, nv0, nv1);
    }

    const char* Kb = (const char*)&Kl[cur][0];
    const unsigned short* Vb = &Vt[cur][0];

    // ---- QK^T swapped: S^T[k][q] ----
    f32x4 s[2][4];
    #pragma unroll
    for (int kt = 0; kt < 4; kt++) {
      int row = kt * 16 + lr;
      int sw = (row & 7) << 4;
      int byteA = (row * 128 + g * 16) ^ sw;
      int byteB = (row * 128 + 64 + g * 16) ^ sw;
      short8 kA = *(const short8*)(Kb + byteA);
      short8 kB = *(const short8*)(Kb + byteB);
      __builtin_amdgcn_s_setprio(1);
      #pragma unroll
      for (int qt = 0; qt < 2; qt++) {
        f32x4 a0 = __builtin_amdgcn_mfma_f32_16x16x32_bf16(kA, qf[qt][0], zero, 0, 0, 0);
        s[qt][kt] = __builtin_amdgcn_mfma_f32_16x16x32_bf16(kB, qf[qt][1], a0, 0, 0, 0);
      }
      __builtin_amdgcn_s_setprio(0);
    }

    // ---- tile max ----
    float nm[2];
    #pragma unroll
    for (int qt = 0; qt < 2; qt++) {
      f32x4 m01 = s[qt][0];
      #pragma unroll
      for (int kt = 1; kt < 4; kt++) {
        f32x4 sv = s[qt][kt];
        m01[0] = fmaxf(m01[0], sv[0]); m01[1] = fmaxf(m01[1], sv[1]);
        m01[2] = fmaxf(m01[2], sv[2]); m01[3] = fmaxf(m01[3], sv[3]);
      }
      float v = fmaxf(fmaxf(m01[0], m01[1]), fmaxf(m01[2], m01[3]));
      v = fmaxf(v, __shfl_xor(v, 16));
      v = fmaxf(v, __shfl_xor(v, 32));
      nm[qt] = v;
    }

    // ---- defer-rescale (THR=8, base-2 domain) ----
    if (!__all(fmaxf(nm[0] - mrun[0], nm[1] - mrun[1]) <= 8.0f)) {
      const int sb = (lane & 48) + ((lane & 48) >> 2);
      #pragma unroll
      for (int qt = 0; qt < 2; qt++) {
        float m2 = fmaxf(mrun[qt], nm[qt]);
        float cc = fexp2(mrun[qt] - m2);
        mrun[qt] = m2;
        lrun[qt] *= cc;
        float c0r = __shfl(cc, sb + 0);
        float c1r = __shfl(cc, sb + 1);
        float c2r = __shfl(cc, sb + 2);
        float c3r = __shfl(cc, sb + 3);
        #pragma unroll
        for (int dv = 0; dv < 4; dv++) {
          f32x4 a = oacc[qt][dv];
          a[0] *= c0r; a[1] *= c1r; a[2] *= c2r; a[3] *= c3r;
          oacc[qt][dv] = a;
        }
      }
    }

    // ---- P = exp2(S - m), packed bf16 -> per-wave LDS ----
    #pragma unroll
    for (int qt = 0; qt < 2; qt++) {
      float mq = mrun[qt];
      float ls = 0.0f;
      unsigned short* prow = qt ? prow1 : prow0;
      #pragma unroll
      for (int kt = 0; kt < 4; kt++) {
        f32x4 sv = s[qt][kt];
        float p0 = fexp2(sv[0] - mq), p1 = fexp2(sv[1] - mq);
        float p2 = fexp2(sv[2] - mq), p3 = fexp2(sv[3] - mq);
        ls += (p0 + p1) + (p2 + p3);
        u32x2 uu;
        uu.x = cvt_pk_bf16(p0, p1);
        uu.y = cvt_pk_bf16(p2, p3);
        *(u32x2*)(prow + kt * 16 + g * 4) = uu;
      }
      ls += __shfl_xor(ls, 16);
      ls += __shfl_xor(ls, 32);
      lrun[qt] += ls;
    }

    // ---- PV ----
    #pragma unroll
    for (int c0 = 0; c0 < 2; c0++) {
      short8 pa0 = *(const short8*)(prow0 + c0 * 32 + g * 8);
      short8 pa1 = *(const short8*)(prow1 + c0 * 32 + g * 8);
      __builtin_amdgcn_s_setprio(1);
      #pragma unroll
      for (int dv = 0; dv < 4; dv++) {
        short8 vf = *(const short8*)&Vb[(dv * 16 + lr) * 72 + c0 * 32 + g * 8];
        oacc[0][dv] = __builtin_amdgcn_mfma_f32_16x16x32_bf16(pa0, vf, oacc[0][dv], 0, 0, 0);
        oacc[1][dv] = __builtin_amdgcn_mfma_f32_16x16x32_bf16(pa1, vf, oacc[1][dv], 0, 0, 0);
      }
      __builtin_amdgcn_s_setprio(0);
    }

    // ---- finish staging chunk i+1 ----
    if (more) {
      VM(0);                       // K DMA + V regs landed (collective via BAR)
      WRITE_V(cur ^ 1, nv0, nv1);
    }
    LGKM0();
    BAR(); FENCE();
  }

  // ---- epilogue: normalize and store [b][n][h*64+d] ----
  const int b = bh >> 5, h = bh & 31;
  const int sb = (lane & 48) + ((lane & 48) >> 2);
  #pragma unroll
  for (int qt = 0; qt < 2; qt++) {
    float inv = 1.0f / lrun[qt];
    float ir[4];
    ir[0] = __shfl(inv, sb + 0);
    ir[1] = __shfl(inv, sb + 1);
    ir[2] = __shfl(inv, sb + 2);
    ir[3] = __shfl(inv, sb + 3);
    #pragma unroll
    for (int r = 0; r < 4; r++) {
      int ntok = q0 + qt * 16 + g * 4 + r;
      size_t ob = ((size_t)(b * NSEQ + ntok)) * DIMC + h * DH;
      #pragma unroll
      for (int dv = 0; dv < 4; dv++)
        aob[ob + dv * 16 + lr] = f2bf(oacc[qt][dv][r] * ir[r]);
    }
  }
}

// ---------------------------------------------------------------------------
extern "C" void kernel_launch(void* const* d_in, const int* in_sizes, int n_in,
                              void* d_out, int out_size, void* d_ws, size_t ws_size,
                              hipStream_t stream) {
  const float* x     = (const float*)d_in[0];
  const float* freqs = (const float*)d_in[1];
  const float* Wqkv  = (const float*)d_in[2];
  const float* Wout  = (const float*)d_in[3];
  float* out = (float*)d_out;

  char* ws = (char*)d_ws;
  size_t off = 0;
  auto alloc = [&](size_t bytes) {
    void* p = ws + off;
    off += (bytes + 255) & ~(size_t)255;
    return p;
  };
  unsigned short* xb    = (unsigned short*)alloc((size_t)MROWS * DIMC * 2);
  unsigned short* wqkvb = (unsigned short*)alloc((size_t)NQKV * DIMC * 2);
  unsigned short* woutb = (unsigned short*)alloc((size_t)DIMC * DIMC * 2);
  unsigned short* qbuf  = (unsigned short*)alloc((size_t)BHEADS * NSEQ * DH * 2);
  unsigned short* kbuf  = (unsigned short*)alloc((size_t)BHEADS * NSEQ * DH * 2);
  unsigned short* vbuf  = (unsigned short*)alloc((size_t)BHEADS * NSEQ * DH * 2);
  float2* cst           = (float2*)alloc((size_t)NSEQ * DH * sizeof(float2));
  unsigned short* aob   = xb;   // xb dead after gemm1; reuse for attn output

  (void)hipFuncSetAttribute((const void*)gemm128<1>,
      hipFuncAttributeMaxDynamicSharedMemorySize, 3 * SLOT);
  (void)hipFuncSetAttribute((const void*)gemm128<0>,
      hipFuncAttributeMaxDynamicSharedMemorySize, 3 * SLOT);

  cvt_all<<<2048, 256, 0, stream>>>(x, Wqkv, Wout, freqs, xb, wqkvb, woutb, cst);

  gemm128<1><<<dim3(NQKV / 256, MROWS / 128), 512, 3 * SLOT, stream>>>(
      xb, wqkvb, DIMC, NQKV, nullptr, qbuf, kbuf, vbuf, cst);

  attn_fa<<<dim3(NSEQ / 128, BHEADS), 256, 0, stream>>>(qbuf, kbuf, vbuf, aob);

  gemm128<0><<<dim3(DIMC / 256, MROWS / 128), 512, 3 * SLOT, stream>>>(
      aob, woutb, DIMC, DIMC, out, nullptr, nullptr, nullptr, nullptr);
}